// Round 10
// baseline (596.700 us; speedup 1.0000x reference)
//
#include <hip/hip_runtime.h>
#include <hip/hip_bf16.h>
#include <cstdint>
#include <cstddef>

// B=2, S=2048, D=1024, H=16, HD=64.  softmax over HEAD axis.
// v9: LDS-pipe attack. attn/den wave q-tile widened to 32 (2 subtiles; each
// LDS fragment read feeds 2x MFMAs -> per-CU LDS instr cycles halved) and the
// Ks [tok][32] panels get an XOR/rotate chunk swizzle (2-way max, free) to
// kill the 8-way b128 bank conflicts. Reader swizzle is constant per lane.

typedef __bf16 bf16x8 __attribute__((ext_vector_type(8)));
typedef __bf16 bf16x4 __attribute__((ext_vector_type(4)));
typedef _Float16 f16x2 __attribute__((ext_vector_type(2)));
typedef _Float16 f16x4 __attribute__((ext_vector_type(4)));
typedef _Float16 f16x8 __attribute__((ext_vector_type(8)));
typedef float floatx4 __attribute__((ext_vector_type(4)));

#define S_LEN 2048
#define DIM 1024
#define NH 16
#define HD 64
#define MTOT 4096  // B * S
#define C_EXP 0.1803368801111244f  // log2(e)/8

__device__ __forceinline__ float fast_exp2(float x) { return __builtin_amdgcn_exp2f(x); }

__device__ __forceinline__ f16x2 pk_cvt(float a, float b) {
    return __builtin_bit_cast(f16x2, __builtin_amdgcn_cvt_pkrtz(a, b));
}

__device__ __forceinline__ void g2l16(const void* g, void* l) {
    __builtin_amdgcn_global_load_lds(
        (const __attribute__((address_space(1))) void*)g,
        (__attribute__((address_space(3))) void*)l, 16, 0, 0);
}

// ---------------- fused cast: x -> bf16, Wq/Wk/Wv -> bf16, Wo -> f16 ----------------
__global__ void cast_all(const float* __restrict__ x,
                         const float* __restrict__ w0, const float* __restrict__ w1,
                         const float* __restrict__ w2, const float* __restrict__ w3,
                         __bf16* __restrict__ xb,
                         __bf16* __restrict__ o0, __bf16* __restrict__ o1,
                         __bf16* __restrict__ o2, _Float16* __restrict__ o3) {
    int bid = blockIdx.x;
    if (bid < 4096) {
        int i = (bid * 256 + threadIdx.x) * 4;
        float4 v = *(const float4*)&x[i];
        bf16x4 o;
        o.x = (__bf16)v.x; o.y = (__bf16)v.y; o.z = (__bf16)v.z; o.w = (__bf16)v.w;
        *(bf16x4*)&xb[i] = o;
        return;
    }
    bid -= 4096;
    int wi = bid >> 10;
    int i = ((bid & 1023) * 256 + threadIdx.x) * 4;
    if (wi == 3) {
        float4 v = *(const float4*)&w3[i];
        f16x4 o;
        o[0] = (_Float16)v.x; o[1] = (_Float16)v.y; o[2] = (_Float16)v.z; o[3] = (_Float16)v.w;
        *(f16x4*)&o3[i] = o;
        return;
    }
    const float* s = (wi == 0) ? w0 : (wi == 1) ? w1 : w2;
    __bf16* d = (wi == 0) ? o0 : (wi == 1) ? o1 : o2;
    float4 v = *(const float4*)&s[i];
    bf16x4 o;
    o.x = (__bf16)v.x; o.y = (__bf16)v.y; o.z = (__bf16)v.z; o.w = (__bf16)v.w;
    *(bf16x4*)&d[i] = o;
}

// ---------------- fused QKV projection GEMM (m97 structure) ----------------
__global__ __launch_bounds__(256, 2) void qkv_gemm(const __bf16* __restrict__ A,
                                                   const __bf16* __restrict__ Wq,
                                                   const __bf16* __restrict__ Wk,
                                                   const __bf16* __restrict__ Wv,
                                                   const float* __restrict__ bq,
                                                   const float* __restrict__ bk,
                                                   const float* __restrict__ bv,
                                                   __bf16* __restrict__ Qo,
                                                   __bf16* __restrict__ Ko,
                                                   _Float16* __restrict__ Vt) {
    const int tng = blockIdx.x * 128, tm = blockIdx.y * 128;
    const int wsel = tng >> 10, tn = tng & 1023;
    const __bf16* W = (wsel == 0) ? Wq : (wsel == 1) ? Wk : Wv;
    const float* bias = (wsel == 0) ? bq : (wsel == 1) ? bk : bv;
    __shared__ __bf16 As[128 * 32];
    __shared__ __bf16 Bs[128 * 32];
    const int tid = threadIdx.x, wid = tid >> 6, lane = tid & 63;
    const int l15 = lane & 15, quad = lane >> 4;
    const int wm = (wid >> 1) * 64, wn = (wid & 1) * 64;
    floatx4 acc[4][4] = {};
    for (int k0 = 0; k0 < DIM; k0 += 32) {
        __syncthreads();
#pragma unroll
        for (int i = 0; i < 2; ++i) {
            int slot = i * 256 + tid;
            int r = slot >> 2, c8 = (slot & 3) * 8;
            g2l16(&A[(size_t)(tm + r) * DIM + k0 + c8], &As[slot * 8]);
            g2l16(&W[(size_t)(tn + r) * DIM + k0 + c8], &Bs[slot * 8]);
        }
        __syncthreads();
        bf16x8 af[4], bf[4];
#pragma unroll
        for (int t = 0; t < 4; ++t) {
            af[t] = *(const bf16x8*)&As[(wm + t * 16 + l15) * 32 + quad * 8];
            bf[t] = *(const bf16x8*)&Bs[(wn + t * 16 + l15) * 32 + quad * 8];
        }
#pragma unroll
        for (int im = 0; im < 4; ++im)
#pragma unroll
            for (int in = 0; in < 4; ++in)
                acc[im][in] = __builtin_amdgcn_mfma_f32_16x16x32_bf16(af[im], bf[in], acc[im][in], 0, 0, 0);
    }
    if (wsel < 2) {
        __bf16* O = wsel ? Ko : Qo;
#pragma unroll
        for (int im = 0; im < 4; ++im)
#pragma unroll
            for (int in = 0; in < 4; ++in)
#pragma unroll
                for (int r = 0; r < 4; ++r) {
                    int row = tm + wm + im * 16 + quad * 4 + r;
                    int col = tn + wn + in * 16 + l15;
                    O[(size_t)row * DIM + col] = (__bf16)(acc[im][in][r] + bias[col]);
                }
    } else {
#pragma unroll
        for (int im = 0; im < 4; ++im)
#pragma unroll
            for (int in = 0; in < 4; ++in) {
                int cv = tn + wn + in * 16 + l15;
                int row4 = tm + wm + im * 16 + quad * 4;
                float bv_ = bias[cv];
                f16x4 o;
#pragma unroll
                for (int r = 0; r < 4; ++r) o[r] = (_Float16)(acc[im][in][r] + bv_);
                *(f16x4*)&Vt[(size_t)cv * MTOT + row4] = o;
            }
    }
}

// ---------------- pass 1: rd = 1/sum_h exp(s/8), Mq=32/wave, swizzled Ks ----------------
// block: 512 thr, 256q x 64k; 2 heads per dbuf iter. grid (32,8,2)=512, 2 blocks/CU.
__global__ __launch_bounds__(512, 4) void den9(const __bf16* __restrict__ Q,
                                               const __bf16* __restrict__ Km,
                                               _Float16* __restrict__ rd) {
    const int kt = blockIdx.x * 64, qt = blockIdx.y * 256, b = blockIdx.z;
    __shared__ __bf16 Ks[2][2 * 2 * 64 * 32];  // 2 bufs x 16 KB: [hs][p][t][32] swizzled
    const int tid = threadIdx.x, wid = tid >> 6, lane = tid & 63;
    const int l15 = lane & 15, quad = lane >> 4;
    const int wq = wid * 32;
    const int sw = (quad + l15 + (l15 >> 2)) & 3;  // reader chunk swizzle (const/lane)
    floatx4 dsum[2][4] = {};
    const size_t qrow0 = (size_t)(b * S_LEN + qt + wq + l15) * DIM;
    const size_t qrow1 = qrow0 + (size_t)16 * DIM;
    const size_t kbase = (size_t)(b * S_LEN + kt) * DIM;
    // staging source (swizzle-inverted), 2 g2l16 per thread per iter
    int sidx[2]; size_t soff[2];
#pragma unroll
    for (int i = 0; i < 2; ++i) {
        int slot = i * 512 + tid;           // 0..1023 chunks
        int hs = slot >> 9, cj = slot & 511;
        int p = cj >> 8, ci = cj & 255;
        int st = ci >> 2, sj = ci & 3;
        int sq = (sj - st - (st >> 2)) & 3;
        sidx[i] = hs;                        // head-subindex
        soff[i] = kbase + (size_t)st * DIM + p * 32 + sq * 8;
    }
    // prologue: stage hh=0
#pragma unroll
    for (int i = 0; i < 2; ++i)
        g2l16(&Km[soff[i] + (0 * 2 + sidx[i]) * HD], &Ks[0][(i * 512 + tid) * 8]);
    for (int hh = 0; hh < 8; ++hh) {
        const int cur = hh & 1, nxt = cur ^ 1;
        __syncthreads();
        // Q frags (issued before next staging -> older in vmcnt FIFO)
        bf16x8 af[2][2][2];  // [hs][sub][frag]
#pragma unroll
        for (int hs = 0; hs < 2; ++hs) {
            int hoff = (hh * 2 + hs) * HD;
            af[hs][0][0] = *(const bf16x8*)&Q[qrow0 + hoff + quad * 8];
            af[hs][0][1] = *(const bf16x8*)&Q[qrow0 + hoff + 32 + quad * 8];
            af[hs][1][0] = *(const bf16x8*)&Q[qrow1 + hoff + quad * 8];
            af[hs][1][1] = *(const bf16x8*)&Q[qrow1 + hoff + 32 + quad * 8];
        }
        if (hh + 1 < 8) {
#pragma unroll
            for (int i = 0; i < 2; ++i)
                g2l16(&Km[soff[i] + ((hh + 1) * 2 + sidx[i]) * HD], &Ks[nxt][(i * 512 + tid) * 8]);
        }
#pragma unroll
        for (int hs = 0; hs < 2; ++hs) {
#pragma unroll
            for (int n = 0; n < 4; ++n) {
                bf16x8 b0 = *(const bf16x8*)&Ks[cur][hs * 4096 + (n * 16 + l15) * 32 + sw * 8];
                bf16x8 b1 = *(const bf16x8*)&Ks[cur][hs * 4096 + 2048 + (n * 16 + l15) * 32 + sw * 8];
#pragma unroll
                for (int sub = 0; sub < 2; ++sub) {
                    floatx4 acc = {};
                    acc = __builtin_amdgcn_mfma_f32_16x16x32_bf16(af[hs][sub][0], b0, acc, 0, 0, 0);
                    acc = __builtin_amdgcn_mfma_f32_16x16x32_bf16(af[hs][sub][1], b1, acc, 0, 0, 0);
                    floatx4 sc = acc * C_EXP;
                    floatx4 e;
#pragma unroll
                    for (int r = 0; r < 4; ++r) e[r] = fast_exp2(sc[r]);
                    dsum[sub][n] += e;
                }
            }
        }
    }
#pragma unroll
    for (int sub = 0; sub < 2; ++sub)
#pragma unroll
        for (int n = 0; n < 4; ++n)
#pragma unroll
            for (int r = 0; r < 4; ++r) {
                int q = qt + wq + sub * 16 + quad * 4 + r;
                int k = kt + n * 16 + l15;
                rd[(size_t)(b * S_LEN + q) * S_LEN + k] = (_Float16)(1.0f / dsum[sub][n][r]);
            }
}

// ---------------- pass 2: partial AO, Mq=32/wave, swizzled Ks ----------------
// block: 512 thr, 256q; k-tile 64, k-split 2 -> grid (16,16,2)=512, 2 blocks/CU.
__global__ __launch_bounds__(512, 4) void attn9(const __bf16* __restrict__ Q,
                                                const __bf16* __restrict__ Km,
                                                const _Float16* __restrict__ Vt,
                                                const _Float16* __restrict__ rd,
                                                _Float16* __restrict__ AO1,
                                                _Float16* __restrict__ AO2) {
    const int qt = (blockIdx.x >> 1) * 256, ks = blockIdx.x & 1;
    const int h = blockIdx.y, b = blockIdx.z;
    __shared__ __bf16 Ks[2][2 * 64 * 32];   // 2 bufs x 8 KB: [p][t][32] swizzled
    __shared__ _Float16 Vts[2][64 * 72];    // 2 bufs x 9 KB, padded [d][ktok]
    const int tid = threadIdx.x, wid = tid >> 6, lane = tid & 63;
    const int l15 = lane & 15, quad = lane >> 4;
    const int wq = wid * 32;
    const int sw = (quad + l15 + (l15 >> 2)) & 3;
    const size_t qrow0 = (size_t)(b * S_LEN + qt + wq + l15) * DIM + h * HD;
    const size_t qrow1 = qrow0 + (size_t)16 * DIM;
    bf16x8 qf[2][2];
    qf[0][0] = *(const bf16x8*)&Q[qrow0 + quad * 8];
    qf[0][1] = *(const bf16x8*)&Q[qrow0 + 32 + quad * 8];
    qf[1][0] = *(const bf16x8*)&Q[qrow1 + quad * 8];
    qf[1][1] = *(const bf16x8*)&Q[qrow1 + 32 + quad * 8];
    const _Float16* rdrow0 = &rd[(size_t)(b * S_LEN + qt + wq + l15) * S_LEN];
    const _Float16* rdrow1 = rdrow0 + (size_t)16 * S_LEN;
    floatx4 oacc[2][4] = {};
    const int kt0 = ks * (S_LEN / 2);
    const size_t kdim = (size_t)b * S_LEN * DIM;
    // V staging index
    const int vr = tid >> 3, vc = (tid & 7) * 8;
    // K staging source (swizzle-inverted): thread writes LDS chunk tid
    const int sp = tid >> 8, sci = tid & 255;
    const int st = sci >> 2, sj = sci & 3;
    const int sq = (sj - st - (st >> 2)) & 3;
    const size_t ksrc = kdim + (size_t)st * DIM + h * HD + sp * 32 + sq * 8;

    // prologue: stage kt0 into buf 0
    {
        f16x8 vtmp = *(const f16x8*)&Vt[(size_t)(h * HD + vr) * MTOT + b * S_LEN + kt0 + vc];
        g2l16(&Km[ksrc + (size_t)kt0 * DIM], &Ks[0][tid * 8]);
        *(f16x8*)&Vts[0][vr * 72 + vc] = vtmp;
    }
    for (int it = 0; it < 16; ++it) {
        const int cur = it & 1, nxt = cur ^ 1;
        const int kt = kt0 + it * 64;
        __syncthreads();
        // rv for this iter (oldest in vmcnt FIFO, covered by QK MFMA)
        f16x4 rv[2][4];
#pragma unroll
        for (int mp = 0; mp < 4; ++mp) {
            rv[0][mp] = *(const f16x4*)&rdrow0[kt + mp * 16 + quad * 4];
            rv[1][mp] = *(const f16x4*)&rdrow1[kt + mp * 16 + quad * 4];
        }
        // issue next tile's loads (V kept in regs; committed to LDS after compute)
        f16x8 vtmp;
        const bool has_next = (it + 1 < 16);
        if (has_next) {
            const int ktn = kt + 64;
            vtmp = *(const f16x8*)&Vt[(size_t)(h * HD + vr) * MTOT + b * S_LEN + ktn + vc];
            g2l16(&Km[ksrc + (size_t)ktn * DIM], &Ks[nxt][tid * 8]);
        }
        // compute current tile
#pragma unroll
        for (int mp = 0; mp < 4; ++mp) {
            bf16x8 kf0 = *(const bf16x8*)&Ks[cur][(mp * 16 + l15) * 32 + sw * 8];
            bf16x8 kf1 = *(const bf16x8*)&Ks[cur][2048 + (mp * 16 + l15) * 32 + sw * 8];
            floatx4 s0 = {}, s1 = {};
            s0 = __builtin_amdgcn_mfma_f32_16x16x32_bf16(kf0, qf[0][0], s0, 0, 0, 0);
            s0 = __builtin_amdgcn_mfma_f32_16x16x32_bf16(kf1, qf[0][1], s0, 0, 0, 0);
            s1 = __builtin_amdgcn_mfma_f32_16x16x32_bf16(kf0, qf[1][0], s1, 0, 0, 0);
            s1 = __builtin_amdgcn_mfma_f32_16x16x32_bf16(kf1, qf[1][1], s1, 0, 0, 0);
            floatx4 c0 = s0 * C_EXP, c1 = s1 * C_EXP;
            f16x2 a01 = pk_cvt(fast_exp2(c0[0]), fast_exp2(c0[1]));
            f16x2 a23 = pk_cvt(fast_exp2(c0[2]), fast_exp2(c0[3]));
            f16x2 b01 = pk_cvt(fast_exp2(c1[0]), fast_exp2(c1[1]));
            f16x2 b23 = pk_cvt(fast_exp2(c1[2]), fast_exp2(c1[3]));
            f16x4 pa0 = __builtin_shufflevector(a01, a23, 0, 1, 2, 3);
            f16x4 pa1 = __builtin_shufflevector(b01, b23, 0, 1, 2, 3);
            pa0 = pa0 * rv[0][mp];
            pa1 = pa1 * rv[1][mp];
#pragma unroll
            for (int n = 0; n < 4; ++n) {
                f16x4 vb = *(const f16x4*)&Vts[cur][(n * 16 + l15) * 72 + mp * 16 + quad * 4];
                oacc[0][n] = __builtin_amdgcn_mfma_f32_16x16x16f16(pa0, vb, oacc[0][n], 0, 0, 0);
                oacc[1][n] = __builtin_amdgcn_mfma_f32_16x16x16f16(pa1, vb, oacc[1][n], 0, 0, 0);
            }
        }
        // commit next V tile to LDS (vmcnt wait lands here, after compute)
        if (has_next) *(f16x8*)&Vts[nxt][vr * 72 + vc] = vtmp;
    }
    _Float16* AO = ks ? AO2 : AO1;
#pragma unroll
    for (int sub = 0; sub < 2; ++sub)
#pragma unroll
        for (int n = 0; n < 4; ++n)
#pragma unroll
            for (int r = 0; r < 4; ++r) {
                int row = qt + wq + sub * 16 + quad * 4 + r;
                int col = h * HD + n * 16 + l15;
                AO[(size_t)(b * S_LEN + row) * DIM + col] = (_Float16)oacc[sub][n][r];
            }
}

// ---------------- output projection: C = (AO1+AO2) @ Wo^T + bo ----------------
__global__ __launch_bounds__(256, 2) void gemm_out2(const _Float16* __restrict__ A1,
                                                    const _Float16* __restrict__ A2,
                                                    const _Float16* __restrict__ Bw,
                                                    const float* __restrict__ bias,
                                                    float* __restrict__ C) {
    const int tm = blockIdx.y * 128, tn = blockIdx.x * 64;
    __shared__ _Float16 As1[2 * 128 * 32];
    __shared__ _Float16 As2[2 * 128 * 32];
    __shared__ _Float16 Bs[2 * 64 * 32];
    const int tid = threadIdx.x, wid = tid >> 6, lane = tid & 63;
    const int l15 = lane & 15, quad = lane >> 4;
    const int wm = (wid >> 1) * 64, wn = (wid & 1) * 32;
    floatx4 acc[4][2] = {};
    for (int k0 = 0; k0 < DIM; k0 += 64) {
        __syncthreads();
#pragma unroll
        for (int i = 0; i < 4; ++i) {
            int slot = i * 256 + tid;
            int p = slot >> 9, rem = slot & 511;
            int r = rem >> 2, c8 = (rem & 3) * 8;
            size_t ga = (size_t)(tm + r) * DIM + k0 + p * 32 + c8;
            g2l16(&A1[ga], &As1[slot * 8]);
            g2l16(&A2[ga], &As2[slot * 8]);
        }
#pragma unroll
        for (int i = 0; i < 2; ++i) {
            int slot = i * 256 + tid;
            int p = slot >> 8, rem = slot & 255;
            int r = rem >> 2, c8 = (rem & 3) * 8;
            g2l16(&Bw[(size_t)(tn + r) * DIM + k0 + p * 32 + c8], &Bs[slot * 8]);
        }
        __syncthreads();
#pragma unroll
        for (int kc = 0; kc < 2; ++kc) {
            f16x8 af[4], bf[2];
#pragma unroll
            for (int t = 0; t < 4; ++t) {
                int off = kc * 4096 + (wm + t * 16 + l15) * 32 + quad * 8;
                f16x8 a1 = *(const f16x8*)&As1[off];
                f16x8 a2 = *(const f16x8*)&As2[off];
                af[t] = a1 + a2;
            }
#pragma unroll
            for (int t = 0; t < 2; ++t)
                bf[t] = *(const f16x8*)&Bs[kc * 2048 + (wn + t * 16 + l15) * 32 + quad * 8];
#pragma unroll
            for (int im = 0; im < 4; ++im)
#pragma unroll
                for (int in = 0; in < 2; ++in)
                    acc[im][in] = __builtin_amdgcn_mfma_f32_16x16x32_f16(af[im], bf[in], acc[im][in], 0, 0, 0);
        }
    }
#pragma unroll
    for (int im = 0; im < 4; ++im)
#pragma unroll
        for (int in = 0; in < 2; ++in)
#pragma unroll
            for (int r = 0; r < 4; ++r) {
                int row = tm + wm + im * 16 + quad * 4 + r;
                int col = tn + wn + in * 16 + l15;
                C[(size_t)row * DIM + col] = acc[im][in][r] + bias[col];
            }
}

extern "C" void kernel_launch(void* const* d_in, const int* in_sizes, int n_in,
                              void* d_out, int out_size, void* d_ws, size_t ws_size,
                              hipStream_t stream) {
    const float* x  = (const float*)d_in[0];
    const float* Wq = (const float*)d_in[1];
    const float* bq = (const float*)d_in[2];
    const float* Wk = (const float*)d_in[3];
    const float* bk = (const float*)d_in[4];
    const float* Wv = (const float*)d_in[5];
    const float* bv = (const float*)d_in[6];
    const float* Wo = (const float*)d_in[7];
    const float* bo = (const float*)d_in[8];
    float* out = (float*)d_out;

    char* ws = (char*)d_ws;
    const size_t MB = 1u << 20;
    __bf16*    xb  = (__bf16*)(ws);              // 8 MB
    __bf16*    Wqb = (__bf16*)(ws + 8 * MB);
    __bf16*    Wkb = (__bf16*)(ws + 10 * MB);
    __bf16*    Wvb = (__bf16*)(ws + 12 * MB);
    _Float16*  Wof = (_Float16*)(ws + 14 * MB);
    __bf16*    Qb  = (__bf16*)(ws + 16 * MB);    // 8 MB
    __bf16*    Kb  = (__bf16*)(ws + 24 * MB);    // 8 MB
    _Float16*  VtH = (_Float16*)(ws + 32 * MB);  // 8 MB
    _Float16*  rd  = (_Float16*)(ws + 40 * MB);  // 8 MB (f16)
    _Float16*  AO1 = (_Float16*)(ws + 56 * MB);  // 8 MB
    _Float16*  AO2 = (_Float16*)(ws + 64 * MB);  // 8 MB

    cast_all<<<8192, 256, 0, stream>>>(x, Wq, Wk, Wv, Wo, xb, Wqb, Wkb, Wvb, Wof);

    qkv_gemm<<<dim3(24, 32), 256, 0, stream>>>(xb, Wqb, Wkb, Wvb, bq, bk, bv, Qb, Kb, VtH);

    den9<<<dim3(S_LEN / 64, S_LEN / 256, 2), 512, 0, stream>>>(Qb, Kb, rd);

    attn9<<<dim3((S_LEN / 256) * 2, NH, 2), 512, 0, stream>>>(Qb, Kb, VtH, rd, AO1, AO2);

    gemm_out2<<<dim3(DIM / 64, MTOT / 128), 256, 0, stream>>>(AO1, AO2, Wof, bo, out);
}

// Round 11
// 270.033 us; speedup vs baseline: 2.2097x; 2.2097x over previous
//
#include <hip/hip_runtime.h>
#include <hip/hip_bf16.h>
#include <cstdint>
#include <cstddef>

// B=2, S=2048, D=1024, H=16, HD=64.  softmax over HEAD axis.
// v10: exact v8b structure (known-good 269 us) + XOR/rotate chunk swizzle on
// the Ks LDS panels in attn/den ONLY. Zero register cost: reader offset
// sw=(quad+l15+(l15>>2))&3 is constant per lane (row terms cancel mod 4);
// writer inverts the swizzle in the g2l16 source address.
// Lesson from v9: Mq=32 widening at 512 thr spills (64-VGPR budget) — reverted.

typedef __bf16 bf16x8 __attribute__((ext_vector_type(8)));
typedef __bf16 bf16x4 __attribute__((ext_vector_type(4)));
typedef _Float16 f16x2 __attribute__((ext_vector_type(2)));
typedef _Float16 f16x4 __attribute__((ext_vector_type(4)));
typedef _Float16 f16x8 __attribute__((ext_vector_type(8)));
typedef float floatx4 __attribute__((ext_vector_type(4)));

#define S_LEN 2048
#define DIM 1024
#define NH 16
#define HD 64
#define MTOT 4096  // B * S
#define C_EXP 0.1803368801111244f  // log2(e)/8

__device__ __forceinline__ float fast_exp2(float x) { return __builtin_amdgcn_exp2f(x); }

__device__ __forceinline__ f16x2 pk_cvt(float a, float b) {
    return __builtin_bit_cast(f16x2, __builtin_amdgcn_cvt_pkrtz(a, b));
}

__device__ __forceinline__ void g2l16(const void* g, void* l) {
    __builtin_amdgcn_global_load_lds(
        (const __attribute__((address_space(1))) void*)g,
        (__attribute__((address_space(3))) void*)l, 16, 0, 0);
}

// ---------------- fused cast: x -> bf16, Wq/Wk/Wv -> bf16, Wo -> f16 ----------------
__global__ void cast_all(const float* __restrict__ x,
                         const float* __restrict__ w0, const float* __restrict__ w1,
                         const float* __restrict__ w2, const float* __restrict__ w3,
                         __bf16* __restrict__ xb,
                         __bf16* __restrict__ o0, __bf16* __restrict__ o1,
                         __bf16* __restrict__ o2, _Float16* __restrict__ o3) {
    int bid = blockIdx.x;
    if (bid < 4096) {
        int i = (bid * 256 + threadIdx.x) * 4;
        float4 v = *(const float4*)&x[i];
        bf16x4 o;
        o.x = (__bf16)v.x; o.y = (__bf16)v.y; o.z = (__bf16)v.z; o.w = (__bf16)v.w;
        *(bf16x4*)&xb[i] = o;
        return;
    }
    bid -= 4096;
    int wi = bid >> 10;
    int i = ((bid & 1023) * 256 + threadIdx.x) * 4;
    if (wi == 3) {
        float4 v = *(const float4*)&w3[i];
        f16x4 o;
        o[0] = (_Float16)v.x; o[1] = (_Float16)v.y; o[2] = (_Float16)v.z; o[3] = (_Float16)v.w;
        *(f16x4*)&o3[i] = o;
        return;
    }
    const float* s = (wi == 0) ? w0 : (wi == 1) ? w1 : w2;
    __bf16* d = (wi == 0) ? o0 : (wi == 1) ? o1 : o2;
    float4 v = *(const float4*)&s[i];
    bf16x4 o;
    o.x = (__bf16)v.x; o.y = (__bf16)v.y; o.z = (__bf16)v.z; o.w = (__bf16)v.w;
    *(bf16x4*)&d[i] = o;
}

// ---------------- fused QKV projection GEMM (m97 structure, untouched) ----------------
__global__ __launch_bounds__(256, 2) void qkv_gemm(const __bf16* __restrict__ A,
                                                   const __bf16* __restrict__ Wq,
                                                   const __bf16* __restrict__ Wk,
                                                   const __bf16* __restrict__ Wv,
                                                   const float* __restrict__ bq,
                                                   const float* __restrict__ bk,
                                                   const float* __restrict__ bv,
                                                   __bf16* __restrict__ Qo,
                                                   __bf16* __restrict__ Ko,
                                                   _Float16* __restrict__ Vt) {
    const int tng = blockIdx.x * 128, tm = blockIdx.y * 128;
    const int wsel = tng >> 10, tn = tng & 1023;
    const __bf16* W = (wsel == 0) ? Wq : (wsel == 1) ? Wk : Wv;
    const float* bias = (wsel == 0) ? bq : (wsel == 1) ? bk : bv;
    __shared__ __bf16 As[128 * 32];
    __shared__ __bf16 Bs[128 * 32];
    const int tid = threadIdx.x, wid = tid >> 6, lane = tid & 63;
    const int l15 = lane & 15, quad = lane >> 4;
    const int wm = (wid >> 1) * 64, wn = (wid & 1) * 64;
    floatx4 acc[4][4] = {};
    for (int k0 = 0; k0 < DIM; k0 += 32) {
        __syncthreads();
#pragma unroll
        for (int i = 0; i < 2; ++i) {
            int slot = i * 256 + tid;
            int r = slot >> 2, c8 = (slot & 3) * 8;
            g2l16(&A[(size_t)(tm + r) * DIM + k0 + c8], &As[slot * 8]);
            g2l16(&W[(size_t)(tn + r) * DIM + k0 + c8], &Bs[slot * 8]);
        }
        __syncthreads();
        bf16x8 af[4], bf[4];
#pragma unroll
        for (int t = 0; t < 4; ++t) {
            af[t] = *(const bf16x8*)&As[(wm + t * 16 + l15) * 32 + quad * 8];
            bf[t] = *(const bf16x8*)&Bs[(wn + t * 16 + l15) * 32 + quad * 8];
        }
#pragma unroll
        for (int im = 0; im < 4; ++im)
#pragma unroll
            for (int in = 0; in < 4; ++in)
                acc[im][in] = __builtin_amdgcn_mfma_f32_16x16x32_bf16(af[im], bf[in], acc[im][in], 0, 0, 0);
    }
    if (wsel < 2) {
        __bf16* O = wsel ? Ko : Qo;
#pragma unroll
        for (int im = 0; im < 4; ++im)
#pragma unroll
            for (int in = 0; in < 4; ++in)
#pragma unroll
                for (int r = 0; r < 4; ++r) {
                    int row = tm + wm + im * 16 + quad * 4 + r;
                    int col = tn + wn + in * 16 + l15;
                    O[(size_t)row * DIM + col] = (__bf16)(acc[im][in][r] + bias[col]);
                }
    } else {
#pragma unroll
        for (int im = 0; im < 4; ++im)
#pragma unroll
            for (int in = 0; in < 4; ++in) {
                int cv = tn + wn + in * 16 + l15;
                int row4 = tm + wm + im * 16 + quad * 4;
                float bv_ = bias[cv];
                f16x4 o;
#pragma unroll
                for (int r = 0; r < 4; ++r) o[r] = (_Float16)(acc[im][in][r] + bv_);
                *(f16x4*)&Vt[(size_t)cv * MTOT + row4] = o;
            }
    }
}

// ---------------- pass 1: rd = 1/sum_h exp(s/8) (f16), swizzled Ks ----------------
// block 128q x 64k, 2 heads per dbuf iter. grid (32,16,2)=1024.
__global__ __launch_bounds__(512, 8) void den10(const __bf16* __restrict__ Q,
                                                const __bf16* __restrict__ Km,
                                                _Float16* __restrict__ rd) {
    const int kt = blockIdx.x * 64, qt = blockIdx.y * 128, b = blockIdx.z;
    __shared__ __bf16 Ks[2][2 * 2 * 64 * 32];  // 2 bufs x 16 KB: [hs][p][t][32] swizzled
    const int tid = threadIdx.x, wid = tid >> 6, lane = tid & 63;
    const int l15 = lane & 15, quad = lane >> 4;
    const int wq = wid * 16;
    const int sw = (quad + l15 + (l15 >> 2)) & 3;  // reader chunk slot (const per lane)
    floatx4 dsum[4] = {};
    const size_t qrow = (size_t)(b * S_LEN + qt + wq + l15) * DIM;
    const size_t kbase = (size_t)(b * S_LEN + kt) * DIM;
    // staging: thread fills LDS chunks {tid, 512+tid}; source chunk is swizzle-inverted
    int shs[2]; size_t soff[2];
#pragma unroll
    for (int i = 0; i < 2; ++i) {
        int slot = i * 512 + tid;            // LDS chunk index 0..1023
        int hs = slot >> 9, rem = slot & 511;
        int p = rem >> 8, rem2 = rem & 255;
        int r = rem2 >> 2, j = rem2 & 3;
        int q = (j - r - (r >> 2)) & 3;      // inverse swizzle
        shs[i] = hs;
        soff[i] = kbase + (size_t)r * DIM + p * 32 + q * 8;
    }
#pragma unroll
    for (int i = 0; i < 2; ++i)
        g2l16(&Km[soff[i] + shs[i] * HD], &Ks[0][(i * 512 + tid) * 8]);
    for (int hh = 0; hh < 8; ++hh) {
        const int cur = hh & 1, nxt = cur ^ 1;
        __syncthreads();
        bf16x8 af[2][2];
#pragma unroll
        for (int hs = 0; hs < 2; ++hs) {
            af[hs][0] = *(const bf16x8*)&Q[qrow + (hh * 2 + hs) * HD + quad * 8];
            af[hs][1] = *(const bf16x8*)&Q[qrow + (hh * 2 + hs) * HD + 32 + quad * 8];
        }
        if (hh + 1 < 8) {
#pragma unroll
            for (int i = 0; i < 2; ++i)
                g2l16(&Km[soff[i] + ((hh + 1) * 2 + shs[i]) * HD], &Ks[nxt][(i * 512 + tid) * 8]);
        }
#pragma unroll
        for (int hs = 0; hs < 2; ++hs) {
#pragma unroll
            for (int n = 0; n < 4; ++n) {
                bf16x8 b0 = *(const bf16x8*)&Ks[cur][hs * 4096 + (n * 16 + l15) * 32 + sw * 8];
                bf16x8 b1 = *(const bf16x8*)&Ks[cur][hs * 4096 + 2048 + (n * 16 + l15) * 32 + sw * 8];
                floatx4 acc = {};
                acc = __builtin_amdgcn_mfma_f32_16x16x32_bf16(af[hs][0], b0, acc, 0, 0, 0);
                acc = __builtin_amdgcn_mfma_f32_16x16x32_bf16(af[hs][1], b1, acc, 0, 0, 0);
                floatx4 sc = acc * C_EXP;
                floatx4 e;
#pragma unroll
                for (int r = 0; r < 4; ++r) e[r] = fast_exp2(sc[r]);
                dsum[n] += e;
            }
        }
    }
#pragma unroll
    for (int n = 0; n < 4; ++n)
#pragma unroll
        for (int r = 0; r < 4; ++r) {
            int q = qt + wq + quad * 4 + r;
            int k = kt + n * 16 + l15;
            rd[(size_t)(b * S_LEN + q) * S_LEN + k] = (_Float16)(1.0f / dsum[n][r]);
        }
}

// ---------------- pass 2: partial AO, swizzled Ks, post-compute V commit ----------------
__global__ __launch_bounds__(512, 8) void attn10(const __bf16* __restrict__ Q,
                                                 const __bf16* __restrict__ Km,
                                                 const _Float16* __restrict__ Vt,
                                                 const _Float16* __restrict__ rd,
                                                 _Float16* __restrict__ AO1,
                                                 _Float16* __restrict__ AO2) {
    const int qt = (blockIdx.x >> 1) * 128, ks = blockIdx.x & 1;
    const int h = blockIdx.y, b = blockIdx.z;
    __shared__ __bf16 Ks[2][2 * 64 * 32];   // 2 bufs x 8 KB: [p][t][32] swizzled
    __shared__ _Float16 Vts[2][64 * 72];    // 2 bufs x 9 KB, padded [d][ktok]
    const int tid = threadIdx.x, wid = tid >> 6, lane = tid & 63;
    const int l15 = lane & 15, quad = lane >> 4;
    const int wq = wid * 16;
    const int sw = (quad + l15 + (l15 >> 2)) & 3;  // reader chunk slot (const per lane)
    const size_t qrow = (size_t)(b * S_LEN + qt + wq + l15) * DIM + h * HD;
    bf16x8 qf0 = *(const bf16x8*)&Q[qrow + quad * 8];
    bf16x8 qf1 = *(const bf16x8*)&Q[qrow + 32 + quad * 8];
    const _Float16* rdrow = &rd[(size_t)(b * S_LEN + qt + wq + l15) * S_LEN];
    floatx4 oacc[4] = {};
    const int kt0 = ks * (S_LEN / 2);
    const size_t kdim = (size_t)b * S_LEN * DIM;
    const int vr = tid >> 3, vc = (tid & 7) * 8;
    // K staging: thread fills LDS chunk tid; source chunk swizzle-inverted
    const int sp = tid >> 8, srem = tid & 255;
    const int sr = srem >> 2, sj = srem & 3;
    const int sq = (sj - sr - (sr >> 2)) & 3;
    const size_t ksrc = kdim + (size_t)sr * DIM + h * HD + sp * 32 + sq * 8;

    // prologue: stage kt0 into buf 0
    {
        f16x8 vtmp = *(const f16x8*)&Vt[(size_t)(h * HD + vr) * MTOT + b * S_LEN + kt0 + vc];
        g2l16(&Km[ksrc + (size_t)kt0 * DIM], &Ks[0][tid * 8]);
        *(f16x8*)&Vts[0][vr * 72 + vc] = vtmp;
    }
    for (int it = 0; it < 16; ++it) {
        const int cur = it & 1, nxt = cur ^ 1;
        const int kt = kt0 + it * 64;
        __syncthreads();
        // rv for this iter (issued first -> oldest in vmcnt FIFO, covered by QK MFMA)
        f16x4 rv[4];
#pragma unroll
        for (int mp = 0; mp < 4; ++mp)
            rv[mp] = *(const f16x4*)&rdrow[kt + mp * 16 + quad * 4];
        // issue next tile's loads (V kept in regs; committed to LDS after compute)
        f16x8 vtmp;
        const bool has_next = (it + 1 < 16);
        if (has_next) {
            const int ktn = kt + 64;
            vtmp = *(const f16x8*)&Vt[(size_t)(h * HD + vr) * MTOT + b * S_LEN + ktn + vc];
            g2l16(&Km[ksrc + (size_t)ktn * DIM], &Ks[nxt][tid * 8]);
        }
        // compute current tile
#pragma unroll
        for (int mp = 0; mp < 4; ++mp) {
            bf16x8 kf0 = *(const bf16x8*)&Ks[cur][(mp * 16 + l15) * 32 + sw * 8];
            bf16x8 kf1 = *(const bf16x8*)&Ks[cur][2048 + (mp * 16 + l15) * 32 + sw * 8];
            floatx4 s = {};
            s = __builtin_amdgcn_mfma_f32_16x16x32_bf16(kf0, qf0, s, 0, 0, 0);
            s = __builtin_amdgcn_mfma_f32_16x16x32_bf16(kf1, qf1, s, 0, 0, 0);
            floatx4 sc = s * C_EXP;
            f16x2 p01 = pk_cvt(fast_exp2(sc[0]), fast_exp2(sc[1]));
            f16x2 p23 = pk_cvt(fast_exp2(sc[2]), fast_exp2(sc[3]));
            f16x4 pa = __builtin_shufflevector(p01, p23, 0, 1, 2, 3);
            pa = pa * rv[mp];  // v_pk_mul_f16 x2
#pragma unroll
            for (int n = 0; n < 4; ++n) {
                f16x4 vb = *(const f16x4*)&Vts[cur][(n * 16 + l15) * 72 + mp * 16 + quad * 4];
                oacc[n] = __builtin_amdgcn_mfma_f32_16x16x16f16(pa, vb, oacc[n], 0, 0, 0);
            }
        }
        // commit next V tile to LDS (vmcnt wait lands here, after compute)
        if (has_next) *(f16x8*)&Vts[nxt][vr * 72 + vc] = vtmp;
    }
    _Float16* AO = ks ? AO2 : AO1;
#pragma unroll
    for (int n = 0; n < 4; ++n)
#pragma unroll
        for (int r = 0; r < 4; ++r) {
            int row = qt + wq + quad * 4 + r;
            int col = h * HD + n * 16 + l15;
            AO[(size_t)(b * S_LEN + row) * DIM + col] = (_Float16)oacc[n][r];
        }
}

// ---------------- output projection: C = (AO1+AO2) @ Wo^T + bo (untouched) ----------------
__global__ __launch_bounds__(256, 2) void gemm_out2(const _Float16* __restrict__ A1,
                                                    const _Float16* __restrict__ A2,
                                                    const _Float16* __restrict__ Bw,
                                                    const float* __restrict__ bias,
                                                    float* __restrict__ C) {
    const int tm = blockIdx.y * 128, tn = blockIdx.x * 64;
    __shared__ _Float16 As1[2 * 128 * 32];
    __shared__ _Float16 As2[2 * 128 * 32];
    __shared__ _Float16 Bs[2 * 64 * 32];
    const int tid = threadIdx.x, wid = tid >> 6, lane = tid & 63;
    const int l15 = lane & 15, quad = lane >> 4;
    const int wm = (wid >> 1) * 64, wn = (wid & 1) * 32;
    floatx4 acc[4][2] = {};
    for (int k0 = 0; k0 < DIM; k0 += 64) {
        __syncthreads();
#pragma unroll
        for (int i = 0; i < 4; ++i) {
            int slot = i * 256 + tid;
            int p = slot >> 9, rem = slot & 511;
            int r = rem >> 2, c8 = (rem & 3) * 8;
            size_t ga = (size_t)(tm + r) * DIM + k0 + p * 32 + c8;
            g2l16(&A1[ga], &As1[slot * 8]);
            g2l16(&A2[ga], &As2[slot * 8]);
        }
#pragma unroll
        for (int i = 0; i < 2; ++i) {
            int slot = i * 256 + tid;
            int p = slot >> 8, rem = slot & 255;
            int r = rem >> 2, c8 = (rem & 3) * 8;
            g2l16(&Bw[(size_t)(tn + r) * DIM + k0 + p * 32 + c8], &Bs[slot * 8]);
        }
        __syncthreads();
#pragma unroll
        for (int kc = 0; kc < 2; ++kc) {
            f16x8 af[4], bf[2];
#pragma unroll
            for (int t = 0; t < 4; ++t) {
                int off = kc * 4096 + (wm + t * 16 + l15) * 32 + quad * 8;
                f16x8 a1 = *(const f16x8*)&As1[off];
                f16x8 a2 = *(const f16x8*)&As2[off];
                af[t] = a1 + a2;
            }
#pragma unroll
            for (int t = 0; t < 2; ++t)
                bf[t] = *(const f16x8*)&Bs[kc * 2048 + (wn + t * 16 + l15) * 32 + quad * 8];
#pragma unroll
            for (int im = 0; im < 4; ++im)
#pragma unroll
                for (int in = 0; in < 2; ++in)
                    acc[im][in] = __builtin_amdgcn_mfma_f32_16x16x32_f16(af[im], bf[in], acc[im][in], 0, 0, 0);
        }
    }
#pragma unroll
    for (int im = 0; im < 4; ++im)
#pragma unroll
        for (int in = 0; in < 2; ++in)
#pragma unroll
            for (int r = 0; r < 4; ++r) {
                int row = tm + wm + im * 16 + quad * 4 + r;
                int col = tn + wn + in * 16 + l15;
                C[(size_t)row * DIM + col] = acc[im][in][r] + bias[col];
            }
}

extern "C" void kernel_launch(void* const* d_in, const int* in_sizes, int n_in,
                              void* d_out, int out_size, void* d_ws, size_t ws_size,
                              hipStream_t stream) {
    const float* x  = (const float*)d_in[0];
    const float* Wq = (const float*)d_in[1];
    const float* bq = (const float*)d_in[2];
    const float* Wk = (const float*)d_in[3];
    const float* bk = (const float*)d_in[4];
    const float* Wv = (const float*)d_in[5];
    const float* bv = (const float*)d_in[6];
    const float* Wo = (const float*)d_in[7];
    const float* bo = (const float*)d_in[8];
    float* out = (float*)d_out;

    char* ws = (char*)d_ws;
    const size_t MB = 1u << 20;
    __bf16*    xb  = (__bf16*)(ws);              // 8 MB
    __bf16*    Wqb = (__bf16*)(ws + 8 * MB);
    __bf16*    Wkb = (__bf16*)(ws + 10 * MB);
    __bf16*    Wvb = (__bf16*)(ws + 12 * MB);
    _Float16*  Wof = (_Float16*)(ws + 14 * MB);
    __bf16*    Qb  = (__bf16*)(ws + 16 * MB);    // 8 MB
    __bf16*    Kb  = (__bf16*)(ws + 24 * MB);    // 8 MB
    _Float16*  VtH = (_Float16*)(ws + 32 * MB);  // 8 MB
    _Float16*  rd  = (_Float16*)(ws + 40 * MB);  // 8 MB (f16)
    _Float16*  AO1 = (_Float16*)(ws + 56 * MB);  // 8 MB
    _Float16*  AO2 = (_Float16*)(ws + 64 * MB);  // 8 MB

    cast_all<<<8192, 256, 0, stream>>>(x, Wq, Wk, Wv, Wo, xb, Wqb, Wkb, Wvb, Wof);

    qkv_gemm<<<dim3(24, 32), 256, 0, stream>>>(xb, Wqb, Wkb, Wvb, bq, bk, bv, Qb, Kb, VtH);

    den10<<<dim3(S_LEN / 64, S_LEN / 128, 2), 512, 0, stream>>>(Qb, Kb, rd);

    attn10<<<dim3((S_LEN / 128) * 2, NH, 2), 512, 0, stream>>>(Qb, Kb, VtH, rd, AO1, AO2);

    gemm_out2<<<dim3(DIM / 64, MTOT / 128), 256, 0, stream>>>(AO1, AO2, Wof, bo, out);
}